// Round 13
// baseline (105.930 us; speedup 1.0000x reference)
//
#include <hip/hip_runtime.h>
#include <hip/hip_bf16.h>

#define NB 4
#define NH 12
#define SEQ 4096
#define DIM 64
#define BH (NB * NH)
#define LOG2E 1.4426950408889634f

typedef __attribute__((ext_vector_type(8))) short short8;
typedef __attribute__((ext_vector_type(4))) float f32x4;
typedef __attribute__((ext_vector_type(2))) unsigned int u32x2;

static __device__ __forceinline__ unsigned int pk2(float a, float b) {
    float2 t; t.x = a; t.y = b;
    union { __hip_bfloat162 h; unsigned int u; } x;
    x.h = __float22bfloat162_rn(t);
    return x.u;
}
static __device__ __forceinline__ short8 mk8(unsigned int a, unsigned int b,
                                             unsigned int c, unsigned int d) {
    union { unsigned int u[4]; short8 s; } x;
    x.u[0] = a; x.u[1] = b; x.u[2] = c; x.u[3] = d;
    return x.s;
}
static __device__ __forceinline__ void gld16(const void* g, void* l) {
    __builtin_amdgcn_global_load_lds(
        (const __attribute__((address_space(1))) unsigned int*)g,
        (__attribute__((address_space(3))) unsigned int*)l,
        16, 0, 0);
}

// ---- prepack K: bf16, pre-swizzled rows Kb[key][d ^ 8*(key&7)] ----
__global__ __launch_bounds__(256)
void prepack_k(const float* __restrict__ K, unsigned short* __restrict__ Kb) {
    const size_t flat = (size_t)blockIdx.x * 256 + threadIdx.x;
    const size_t key  = flat >> 3;
    const int    c    = (int)(flat & 7);
    const float* kp = K + key * 64 + 8 * c;
    f32x4 a = *reinterpret_cast<const f32x4*>(kp);
    f32x4 b = *reinterpret_cast<const f32x4*>(kp + 4);
    short8 o = mk8(pk2(a[0], a[1]), pk2(a[2], a[3]), pk2(b[0], b[1]), pk2(b[2], b[3]));
    *reinterpret_cast<short8*>(Kb + key * 64 + ((8 * c) ^ (8 * ((int)key & 7)))) = o;
}

// ---- prepack V: bf16 transposed, pre-swizzled Vb[bh][d][k ^ 8*((d^(d>>2))&7)] ----
__global__ __launch_bounds__(256)
void prepack_v(const float* __restrict__ V, unsigned short* __restrict__ Vb) {
    __shared__ unsigned short T[64][256];   // T[d][key ^ 8*((d>>2)&7)]
    const int bid = blockIdx.x;
    const int kt  = bid & 15;
    const int bh  = bid >> 4;
    const float* Vp = V + ((size_t)bh * SEQ + kt * 256) * DIM;
    const int tid = threadIdx.x;
    const int c   = tid & 15;
    const int c4  = 4 * c;
    const int sw  = 8 * (c & 7);            // (d>>2)&7 == c&7 for d = 4c+i
    #pragma unroll
    for (int rr = 0; rr < 16; ++rr) {
        const int key = (tid >> 4) + 16 * rr;
        f32x4 v = *reinterpret_cast<const f32x4*>(Vp + (size_t)key * DIM + c4);
        T[c4 + 0][key ^ sw] = (unsigned short)(pk2(v[0], v[0]) & 0xffff);
        T[c4 + 1][key ^ sw] = (unsigned short)(pk2(v[1], v[1]) & 0xffff);
        T[c4 + 2][key ^ sw] = (unsigned short)(pk2(v[2], v[2]) & 0xffff);
        T[c4 + 3][key ^ sw] = (unsigned short)(pk2(v[3], v[3]) & 0xffff);
    }
    __syncthreads();
    #pragma unroll
    for (int q = 0; q < 8; ++q) {
        const int d    = 8 * q + (tid >> 5);
        const int col0 = (tid & 31) * 8;
        const int swd  = 8 * ((d >> 2) & 7);
        const int gd   = (d ^ (d >> 2)) & 7;
        short8 val = *reinterpret_cast<const short8*>(&T[d][col0 ^ swd]);
        *reinterpret_cast<short8*>(
            Vb + ((size_t)bh * DIM + d) * SEQ + kt * 256 + (col0 ^ (8 * gd))) = val;
    }
}

// ---- main kernel: 2 windows/block, 80 KB LDS -> 2 independent blocks/CU ----
__global__ __launch_bounds__(512, 4)
void blk_attn(const float* __restrict__ Q, const float* __restrict__ K,
              const float* __restrict__ V, const float* __restrict__ M,
              float* __restrict__ O,
              const unsigned short* __restrict__ Kb,
              const unsigned short* __restrict__ Vb, int use_pre) {
    int bid = blockIdx.x;
    bid = (bid & 7) * 192 + (bid >> 3);   // XCD swizzle (1536 % 8 == 0)

    const int j  = bid & 31;
    const int bh = bid >> 5;
    const int b  = bh / NH;

    const size_t base = (size_t)bh * SEQ * DIM;
    const float* Kp = K + base;
    const float* Vp = V + base;

    const int tid  = threadIdx.x;
    const int w    = tid >> 6;
    const int lane = tid & 63;
    const int lo   = lane & 15;
    const int hi   = lane >> 4;

    const float wtA = (j == 0)  ? 0.f : ((j == 31) ? 1.f : 0.5f);
    const float wtB = (j == 31) ? 0.f : ((j == 0)  ? 1.f : 0.5f);

    __shared__ __align__(16) unsigned char smem[81920];
    auto Ks = (unsigned short (*)[64])(smem);            // [256][64]: K[key][d ^ 8*(key&7)]
    auto Vt = (unsigned short (*)[256])(smem + 32768);   // [64][256]: V^T[d][k ^ 8*((d^(d>>2))&7)]
    auto Pw = (unsigned int (*)[16][32])(smem + 65536);  // [8 waves][16 q][32 dw]

    short8 qa[2];
    {
        const float qs = 0.125f * LOG2E;
        const float* qr = Q + base + (size_t)(128 * j + 16 * w + lo) * DIM + hi * 8;
        #pragma unroll
        for (int s = 0; s < 2; ++s) {
            f32x4 a = *reinterpret_cast<const f32x4*>(qr + 32 * s);
            f32x4 c = *reinterpret_cast<const f32x4*>(qr + 32 * s + 4);
            qa[s] = mk8(pk2(a[0] * qs, a[1] * qs), pk2(a[2] * qs, a[3] * qs),
                        pk2(c[0] * qs, c[1] * qs), pk2(c[2] * qs, c[3] * qs));
        }
    }

    f32x4 fin[4];
    #pragma unroll
    for (int dt = 0; dt < 4; ++dt) { fin[dt][0]=0.f; fin[dt][1]=0.f; fin[dt][2]=0.f; fin[dt][3]=0.f; }

    const int c8 = lane & 7, r8 = lane >> 3;
    const int quad = lane & 3, colq = lane >> 2;
    const int kswz = 8 * (lo & 7);
    const int pswz = 4 * (lo & 7);

    #pragma unroll
    for (int wi = 0; wi < 2; ++wi) {
        const float wt = wi ? wtB : wtA;
        if (wt == 0.f) continue;                 // block-uniform
        const int kw = 128 * j - 128 + 128 * wi; // window base in [0, 3840]

        if (wi == 1 && wtA != 0.f) __syncthreads();

        if (use_pre) {
            // pure DMA staging: 4 K-chunks + 4 V-chunks per wave, 1 KB each
            const unsigned short* Kbp = Kb + ((size_t)bh * SEQ + kw) * DIM;
            const unsigned short* Vbp = Vb + (size_t)bh * DIM * SEQ + kw;
            #pragma unroll
            for (int c = 0; c < 4; ++c) {
                const int tk = 4 * w + c;
                gld16(Kbp + (size_t)tk * 512 + (lane >> 3) * 64 + (lane & 7) * 8,
                      (unsigned short*)Ks + tk * 512);
                gld16(Vbp + (size_t)(2 * tk + (lane >> 5)) * SEQ + (lane & 31) * 8,
                      (unsigned short*)Vt + tk * 512);
            }
        } else {
            #pragma unroll
            for (int it = 0; it < 4; ++it) {
                const int row = 32 * w + 8 * it + r8;
                const float* kp = Kp + (size_t)(kw + row) * DIM + 8 * c8;
                f32x4 a = *reinterpret_cast<const f32x4*>(kp);
                f32x4 c = *reinterpret_cast<const f32x4*>(kp + 4);
                *reinterpret_cast<short8*>(&Ks[row][(8 * c8) ^ (8 * r8)]) =
                    mk8(pk2(a[0], a[1]), pk2(a[2], a[3]), pk2(c[0], c[1]), pk2(c[2], c[3]));
            }
            #pragma unroll
            for (int it = 0; it < 2; ++it) {
                const int kg = 2 * w + it;
                const int k0 = 16 * kg + 4 * quad;
                f32x4 vr[4];
                #pragma unroll
                for (int kk = 0; kk < 4; ++kk)
                    vr[kk] = *reinterpret_cast<const f32x4*>(
                        Vp + (size_t)(kw + k0 + kk) * DIM + 4 * colq);
                #pragma unroll
                for (int i = 0; i < 4; ++i) {
                    const int d  = 4 * colq + i;
                    const int gd = (d ^ (d >> 2)) & 7;
                    u32x2 o;
                    o[0] = pk2(vr[0][i], vr[1][i]);
                    o[1] = pk2(vr[2][i], vr[3][i]);
                    *reinterpret_cast<u32x2*>(&Vt[d][k0 ^ (8 * gd)]) = o;
                }
            }
        }
        __syncthreads();   // drains vmcnt(0): DMA complete

        // ---- QK^T swapped: st[l] = S[key=16l+4hi+r][q=lo] ----
        f32x4 st[16];
        #pragma unroll
        for (int l = 0; l < 16; ++l) { st[l][0]=0.f; st[l][1]=0.f; st[l][2]=0.f; st[l][3]=0.f; }
        __builtin_amdgcn_s_setprio(1);
        #pragma unroll
        for (int s = 0; s < 2; ++s)
            #pragma unroll
            for (int l = 0; l < 16; ++l) {
                short8 kf = *reinterpret_cast<const short8*>(
                    &Ks[16 * l + lo][(32 * s + 8 * hi) ^ kswz]);
                st[l] = __builtin_amdgcn_mfma_f32_16x16x32_bf16(kf, qa[s], st[l], 0, 0, 0);
            }
        __builtin_amdgcn_s_setprio(0);

        // ---- mask ----
        const float* Mq = M + (size_t)b * SEQ + kw;
        #pragma unroll
        for (int l = 0; l < 16; ++l) {
            f32x4 mv = *reinterpret_cast<const f32x4*>(Mq + 16 * l + 4 * hi);
            #pragma unroll
            for (int r = 0; r < 4; ++r) st[l][r] = fmaf(mv[r], LOG2E, st[l][r]);
        }

        // ---- exact softmax over the window (q = lo, lane-local) ----
        float mx = st[0][0];
        #pragma unroll
        for (int l = 0; l < 16; ++l)
            #pragma unroll
            for (int r = 0; r < 4; ++r) mx = fmaxf(mx, st[l][r]);
        mx = fmaxf(mx, __shfl_xor(mx, 16));
        mx = fmaxf(mx, __shfl_xor(mx, 32));
        #pragma unroll
        for (int l = 0; l < 16; ++l)
            #pragma unroll
            for (int r = 0; r < 4; ++r) st[l][r] = exp2f(st[l][r] - mx);
        float S = 0.f;
        #pragma unroll
        for (int l = 0; l < 16; ++l)
            S += (st[l][0] + st[l][1]) + (st[l][2] + st[l][3]);
        S += __shfl_xor(S, 16); S += __shfl_xor(S, 32);

        // ---- PV swapped (O^T): 8 kq of 32 keys ----
        f32x4 acc[4];
        #pragma unroll
        for (int dt = 0; dt < 4; ++dt) { acc[dt][0]=0.f; acc[dt][1]=0.f; acc[dt][2]=0.f; acc[dt][3]=0.f; }
        #pragma unroll
        for (int kq = 0; kq < 8; ++kq) {
            const int pp = 16 * (kq & 1);
            u32x2 w0v, w1v;
            w0v[0] = pk2(st[2 * kq][0],     st[2 * kq][1]);
            w0v[1] = pk2(st[2 * kq][2],     st[2 * kq][3]);
            w1v[0] = pk2(st[2 * kq + 1][0], st[2 * kq + 1][1]);
            w1v[1] = pk2(st[2 * kq + 1][2], st[2 * kq + 1][3]);
            *reinterpret_cast<u32x2*>(&Pw[w][lo][(pp + 2 * hi)     ^ pswz]) = w0v;
            *reinterpret_cast<u32x2*>(&Pw[w][lo][(pp + 8 + 2 * hi) ^ pswz]) = w1v;
            short8 pf = *reinterpret_cast<const short8*>(&Pw[w][lo][(pp + 4 * hi) ^ pswz]);
            __builtin_amdgcn_s_setprio(1);
            #pragma unroll
            for (int dt = 0; dt < 4; ++dt) {
                const int d  = 16 * dt + lo;
                const int gd = (d ^ (d >> 2)) & 7;
                short8 vf = *reinterpret_cast<const short8*>(
                    &Vt[d][(32 * kq + 8 * hi) ^ (8 * gd)]);
                acc[dt] = __builtin_amdgcn_mfma_f32_16x16x32_bf16(vf, pf, acc[dt], 0, 0, 0);
            }
            __builtin_amdgcn_s_setprio(0);
        }

        const float coef = wt / S;
        #pragma unroll
        for (int dt = 0; dt < 4; ++dt)
            #pragma unroll
            for (int r = 0; r < 4; ++r) fin[dt][r] = fmaf(coef, acc[dt][r], fin[dt][r]);
    }

    float* Opr = O + base + (size_t)(128 * j + 16 * w + lo) * DIM + 4 * hi;
    #pragma unroll
    for (int dt = 0; dt < 4; ++dt)
        *reinterpret_cast<f32x4*>(Opr + 16 * dt) = fin[dt];
}

extern "C" void kernel_launch(void* const* d_in, const int* in_sizes, int n_in,
                              void* d_out, int out_size, void* d_ws, size_t ws_size,
                              hipStream_t stream) {
    const float* Q = (const float*)d_in[0];
    const float* K = (const float*)d_in[1];
    const float* V = (const float*)d_in[2];
    const float* M = (const float*)d_in[3];
    float* O = (float*)d_out;

    const size_t PK_BYTES = (size_t)BH * SEQ * DIM * 2;   // 25,165,824
    const bool pre = ws_size >= 2 * PK_BYTES;
    unsigned short* Kb = (unsigned short*)d_ws;
    unsigned short* Vb = (unsigned short*)((char*)d_ws + PK_BYTES);

    if (pre) {
        prepack_k<<<dim3((size_t)BH * SEQ * DIM / (256 * 8)), dim3(256), 0, stream>>>(K, Kb);
        prepack_v<<<dim3(BH * (SEQ / 256)), dim3(256), 0, stream>>>(V, Vb);
    }
    blk_attn<<<dim3(NB * NH * (SEQ / 128)), dim3(512), 0, stream>>>(
        Q, K, V, M, O, Kb, Vb, pre ? 1 : 0);
}

// Round 14
// 90.890 us; speedup vs baseline: 1.1655x; 1.1655x over previous
//
#include <hip/hip_runtime.h>
#include <hip/hip_bf16.h>

#define NB 4
#define NH 12
#define SEQ 4096
#define DIM 64
#define LOG2E 1.4426950408889634f

typedef __attribute__((ext_vector_type(8))) short short8;
typedef __attribute__((ext_vector_type(4))) float f32x4;
typedef __attribute__((ext_vector_type(2))) unsigned int u32x2;

static __device__ __forceinline__ unsigned int pk2(float a, float b) {
    float2 t; t.x = a; t.y = b;
    union { __hip_bfloat162 h; unsigned int u; } x;
    x.h = __float22bfloat162_rn(t);
    return x.u;
}
static __device__ __forceinline__ short8 mk8(unsigned int a, unsigned int b,
                                             unsigned int c, unsigned int d) {
    union { unsigned int u[4]; short8 s; } x;
    x.u[0] = a; x.u[1] = b; x.u[2] = c; x.u[3] = d;
    return x.s;
}

__global__ __launch_bounds__(512, 2)
void blk_attn(const float* __restrict__ Q, const float* __restrict__ K,
              const float* __restrict__ V, const float* __restrict__ M,
              float* __restrict__ O) {
    int bid = blockIdx.x;
    bid = (bid & 7) * 192 + (bid >> 3);   // XCD swizzle: 1 bh resident/XCD ≈ 2.2MB < 4MB L2

    const int j  = bid & 31;
    const int bh = bid >> 5;
    const int b  = bh / NH;

    const size_t base = (size_t)bh * SEQ * DIM;
    const float* Kp = K + base;
    const float* Vp = V + base;

    const int tid  = threadIdx.x;
    const int w    = tid >> 6;      // wave 0..7, owns queries [16w, 16w+16)
    const int lane = tid & 63;
    const int lo   = lane & 15;
    const int hi   = lane >> 4;

    // span [kb0, kb0+384): W0 = tiles 0..15, W1 = tiles 8..23 (always in-bounds)
    const int  kb0 = (j == 0) ? 0 : ((j == 31) ? SEQ - 384 : 128 * j - 128);
    const bool md  = (j != 0) && (j != 31);
    const float wt0 = (j == 31) ? 0.f : (md ? 0.5f : 1.f);
    const float wt1 = (j == 0)  ? 0.f : (md ? 0.5f : 1.f);

    // ---- LDS: 112 KB ----
    __shared__ __align__(16) unsigned char smem[114688];
    auto Ks = (unsigned short (*)[64])(smem);            // [384][64]: K[key][d ^ 8*(key&7)]
    auto Vt = (unsigned short (*)[384])(smem + 49152);   // [64][384]: V^T[d][k ^ 8*((d^(d>>2))&7)]
    auto Pw = (unsigned int (*)[16][32])(smem + 98304);  // [8 waves][16 q][32 dw]

    // ---- Q fragments, scaled by log2e/8 ----
    short8 qa[2];
    {
        const float qs = 0.125f * LOG2E;
        const float* qr = Q + base + (size_t)(128 * j + 16 * w + lo) * DIM + hi * 8;
        #pragma unroll
        for (int s = 0; s < 2; ++s) {
            f32x4 a = *reinterpret_cast<const f32x4*>(qr + 32 * s);
            f32x4 c = *reinterpret_cast<const f32x4*>(qr + 32 * s + 4);
            qa[s] = mk8(pk2(a[0] * qs, a[1] * qs), pk2(a[2] * qs, a[3] * qs),
                        pk2(c[0] * qs, c[1] * qs), pk2(c[2] * qs, c[3] * qs));
        }
    }

    const int c8 = lane & 7, r8 = lane >> 3;
    const int quad = lane & 3, colq = lane >> 2;
    const int kswz = 8 * (lo & 7);
    const int pswz = 4 * (lo & 7);

    // ================= stage 0: keys [0, 192) =================
    #pragma unroll
    for (int it = 0; it < 3; ++it) {
        const int row = 8 * w + r8 + 64 * it;            // 0..191, row&7 == r8
        const float* kp = Kp + (size_t)(kb0 + row) * DIM + 8 * c8;
        f32x4 a = *reinterpret_cast<const f32x4*>(kp);
        f32x4 c = *reinterpret_cast<const f32x4*>(kp + 4);
        *reinterpret_cast<short8*>(&Ks[row][(8 * c8) ^ (8 * r8)]) =
            mk8(pk2(a[0], a[1]), pk2(a[2], a[3]), pk2(c[0], c[1]), pk2(c[2], c[3]));
    }
    #pragma unroll
    for (int it = 0; it < 2; ++it) {
        const int kg = w + 8 * it;                       // wave-uniform; kg 0..11
        if (kg < 12) {
            const int k0 = 16 * kg + 4 * quad;
            f32x4 vr[4];
            #pragma unroll
            for (int kk = 0; kk < 4; ++kk)
                vr[kk] = *reinterpret_cast<const f32x4*>(
                    Vp + (size_t)(kb0 + k0 + kk) * DIM + 4 * colq);
            #pragma unroll
            for (int i = 0; i < 4; ++i) {
                const int d  = 4 * colq + i;
                const int gd = (d ^ (d >> 2)) & 7;
                u32x2 o;
                o[0] = pk2(vr[0][i], vr[1][i]);
                o[1] = pk2(vr[2][i], vr[3][i]);
                *reinterpret_cast<u32x2*>(&Vt[d][k0 ^ (8 * gd)]) = o;
            }
        }
    }
    __syncthreads();   // barrier 1: stage-0 visible

    // ===== issue stage-1 loads (keys [192, 384)) — held in regs (T14) =====
    f32x4 k1a[3], k1c[3];
    #pragma unroll
    for (int it = 0; it < 3; ++it) {
        const int row = 8 * w + r8 + 192 + 64 * it;
        const float* kp = Kp + (size_t)(kb0 + row) * DIM + 8 * c8;
        k1a[it] = *reinterpret_cast<const f32x4*>(kp);
        k1c[it] = *reinterpret_cast<const f32x4*>(kp + 4);
    }
    f32x4 v1a[4], v1b[4];
    {
        const int k0 = 16 * (12 + w) + 4 * quad;         // kg 12..19
        #pragma unroll
        for (int kk = 0; kk < 4; ++kk)
            v1a[kk] = *reinterpret_cast<const f32x4*>(
                Vp + (size_t)(kb0 + k0 + kk) * DIM + 4 * colq);
    }
    if (w < 4) {
        const int k0 = 16 * (20 + w) + 4 * quad;         // kg 20..23
        #pragma unroll
        for (int kk = 0; kk < 4; ++kk)
            v1b[kk] = *reinterpret_cast<const f32x4*>(
                Vp + (size_t)(kb0 + k0 + kk) * DIM + 4 * colq);
    }

    float m = -3.0e38f, S0 = 0.f, S1 = 0.f;
    f32x4 accX[4], accY[4];
    #pragma unroll
    for (int dt = 0; dt < 4; ++dt) {
        accX[dt][0]=0.f; accX[dt][1]=0.f; accX[dt][2]=0.f; accX[dt][3]=0.f;
        accY[dt][0]=0.f; accY[dt][1]=0.f; accY[dt][2]=0.f; accY[dt][3]=0.f;
    }
    const float* Mq = M + (size_t)b * SEQ + kb0;

    #pragma unroll
    for (int ps = 0; ps < 2; ++ps) {
        if (ps) {
            // ---- write stage-1 from regs (loads drained by compiler vmcnt) ----
            #pragma unroll
            for (int it = 0; it < 3; ++it) {
                const int row = 8 * w + r8 + 192 + 64 * it;
                *reinterpret_cast<short8*>(&Ks[row][(8 * c8) ^ (8 * r8)]) =
                    mk8(pk2(k1a[it][0], k1a[it][1]), pk2(k1a[it][2], k1a[it][3]),
                        pk2(k1c[it][0], k1c[it][1]), pk2(k1c[it][2], k1c[it][3]));
            }
            {
                const int k0 = 16 * (12 + w) + 4 * quad;
                #pragma unroll
                for (int i = 0; i < 4; ++i) {
                    const int d  = 4 * colq + i;
                    const int gd = (d ^ (d >> 2)) & 7;
                    u32x2 o;
                    o[0] = pk2(v1a[0][i], v1a[1][i]);
                    o[1] = pk2(v1a[2][i], v1a[3][i]);
                    *reinterpret_cast<u32x2*>(&Vt[d][k0 ^ (8 * gd)]) = o;
                }
            }
            if (w < 4) {
                const int k0 = 16 * (20 + w) + 4 * quad;
                #pragma unroll
                for (int i = 0; i < 4; ++i) {
                    const int d  = 4 * colq + i;
                    const int gd = (d ^ (d >> 2)) & 7;
                    u32x2 o;
                    o[0] = pk2(v1b[0][i], v1b[1][i]);
                    o[1] = pk2(v1b[2][i], v1b[3][i]);
                    *reinterpret_cast<u32x2*>(&Vt[d][k0 ^ (8 * gd)]) = o;
                }
            }
            __syncthreads();   // barrier 2: stage-1 visible
        }
        const int kb = 192 * ps;

        // ---- QK^T swapped: st[l] = S[key=16l+4hi+r][q=lo] ----
        f32x4 st[12];
        #pragma unroll
        for (int l = 0; l < 12; ++l) { st[l][0]=0.f; st[l][1]=0.f; st[l][2]=0.f; st[l][3]=0.f; }
        __builtin_amdgcn_s_setprio(1);
        #pragma unroll
        for (int s = 0; s < 2; ++s)
            #pragma unroll
            for (int l = 0; l < 12; ++l) {
                short8 kf = *reinterpret_cast<const short8*>(
                    &Ks[kb + 16 * l + lo][(32 * s + 8 * hi) ^ kswz]);
                st[l] = __builtin_amdgcn_mfma_f32_16x16x32_bf16(kf, qa[s], st[l], 0, 0, 0);
            }
        __builtin_amdgcn_s_setprio(0);

        // ---- mask (global, L2-resident; pre-scaled by log2e) ----
        #pragma unroll
        for (int l = 0; l < 12; ++l) {
            f32x4 mv = *reinterpret_cast<const f32x4*>(Mq + kb + 16 * l + 4 * hi);
            #pragma unroll
            for (int r = 0; r < 4; ++r) st[l][r] = fmaf(mv[r], LOG2E, st[l][r]);
        }

        // ---- online softmax (q = lo, lane-local), TREE reductions ----
        float tm[12];
        #pragma unroll
        for (int l = 0; l < 12; ++l)
            tm[l] = fmaxf(fmaxf(st[l][0], st[l][1]), fmaxf(st[l][2], st[l][3]));
        float mx = fmaxf(fmaxf(fmaxf(fmaxf(tm[0], tm[1]), fmaxf(tm[2], tm[3])),
                               fmaxf(fmaxf(tm[4], tm[5]), fmaxf(tm[6], tm[7]))),
                         fmaxf(fmaxf(tm[8], tm[9]), fmaxf(tm[10], tm[11])));
        mx = fmaxf(mx, __shfl_xor(mx, 16));
        mx = fmaxf(mx, __shfl_xor(mx, 32));
        const float mn = fmaxf(m, mx);
        if (ps) {
            const float f = exp2f(m - mn);   // lane-local: acc is O^T layout (q = lo)
            S0 *= f; S1 *= f;
            #pragma unroll
            for (int dt = 0; dt < 4; ++dt)
                #pragma unroll
                for (int r = 0; r < 4; ++r) { accX[dt][r] *= f; accY[dt][r] *= f; }
        }
        m = mn;

        #pragma unroll
        for (int l = 0; l < 12; ++l)
            #pragma unroll
            for (int r = 0; r < 4; ++r) st[l][r] = exp2f(st[l][r] - m);

        // row sums per tile, then trees; W0 = tiles 0..15, W1 = 8..23 (T = 12ps+l)
        float ts[12];
        #pragma unroll
        for (int l = 0; l < 12; ++l)
            ts[l] = (st[l][0] + st[l][1]) + (st[l][2] + st[l][3]);
        const float t4a = (ts[0] + ts[1]) + (ts[2] + ts[3]);
        const float t4b = (ts[4] + ts[5]) + (ts[6] + ts[7]);
        const float t4c = (ts[8] + ts[9]) + (ts[10] + ts[11]);
        const float tAll = (t4a + t4b) + t4c;
        if (ps == 0) { S0 += tAll; S1 += t4c; }
        else         { S0 += t4a;  S1 += tAll; }

        // ---- pack P (unweighted) ----
        unsigned int pk[24];
        #pragma unroll
        for (int l = 0; l < 12; ++l) {
            pk[2 * l]     = pk2(st[l][0], st[l][1]);
            pk[2 * l + 1] = pk2(st[l][2], st[l][3]);
        }

        // ---- PV swapped (O^T): overlap tiles feed both accumulators ----
        #pragma unroll
        for (int kq = 0; kq < 6; ++kq) {
            const int pp = 16 * (kq & 1);
            u32x2 w0v, w1v;
            w0v[0] = pk[4 * kq + 0]; w0v[1] = pk[4 * kq + 1];
            w1v[0] = pk[4 * kq + 2]; w1v[1] = pk[4 * kq + 3];
            *reinterpret_cast<u32x2*>(&Pw[w][lo][(pp + 2 * hi)     ^ pswz]) = w0v;
            *reinterpret_cast<u32x2*>(&Pw[w][lo][(pp + 8 + 2 * hi) ^ pswz]) = w1v;
            short8 pf = *reinterpret_cast<const short8*>(&Pw[w][lo][(pp + 4 * hi) ^ pswz]);
            const bool toX = (ps == 0) ? true : (kq < 2);
            const bool toY = (ps == 0) ? (kq >= 4) : true;
            __builtin_amdgcn_s_setprio(1);
            #pragma unroll
            for (int dt = 0; dt < 4; ++dt) {
                const int d  = 16 * dt + lo;
                const int gd = (d ^ (d >> 2)) & 7;
                short8 vf = *reinterpret_cast<const short8*>(
                    &Vt[d][(kb + 32 * kq + 8 * hi) ^ (8 * gd)]);
                if (toX) accX[dt] = __builtin_amdgcn_mfma_f32_16x16x32_bf16(vf, pf, accX[dt], 0, 0, 0);
                if (toY) accY[dt] = __builtin_amdgcn_mfma_f32_16x16x32_bf16(vf, pf, accY[dt], 0, 0, 0);
            }
            __builtin_amdgcn_s_setprio(0);
        }
    }

    // ---- finalize: lane-local (q = lo), contiguous f32x4 store ----
    S0 += __shfl_xor(S0, 16); S0 += __shfl_xor(S0, 32);
    S1 += __shfl_xor(S1, 16); S1 += __shfl_xor(S1, 32);
    const float b0 = wt0 / S0;
    const float b1 = wt1 / S1;
    float* Opr = O + base + (size_t)(128 * j + 16 * w + lo) * DIM + 4 * hi;
    #pragma unroll
    for (int dt = 0; dt < 4; ++dt) {
        f32x4 o;
        #pragma unroll
        for (int r = 0; r < 4; ++r) o[r] = b0 * accX[dt][r] + b1 * accY[dt][r];
        *reinterpret_cast<f32x4*>(Opr + 16 * dt) = o;
    }
}

extern "C" void kernel_launch(void* const* d_in, const int* in_sizes, int n_in,
                              void* d_out, int out_size, void* d_ws, size_t ws_size,
                              hipStream_t stream) {
    const float* Q = (const float*)d_in[0];
    const float* K = (const float*)d_in[1];
    const float* V = (const float*)d_in[2];
    const float* M = (const float*)d_in[3];
    float* O = (float*)d_out;
    blk_attn<<<dim3(NB * NH * (SEQ / 128)), dim3(512), 0, stream>>>(Q, K, V, M, O);
}

// Round 15
// 89.484 us; speedup vs baseline: 1.1838x; 1.0157x over previous
//
#include <hip/hip_runtime.h>
#include <hip/hip_bf16.h>

#define NB 4
#define NH 12
#define SEQ 4096
#define DIM 64
#define LOG2E 1.4426950408889634f

typedef __attribute__((ext_vector_type(8))) short short8;
typedef __attribute__((ext_vector_type(4))) float f32x4;
typedef __attribute__((ext_vector_type(2))) unsigned int u32x2;

static __device__ __forceinline__ unsigned int pk2(float a, float b) {
    float2 t; t.x = a; t.y = b;
    union { __hip_bfloat162 h; unsigned int u; } x;
    x.h = __float22bfloat162_rn(t);
    return x.u;
}
static __device__ __forceinline__ short8 mk8(unsigned int a, unsigned int b,
                                             unsigned int c, unsigned int d) {
    union { unsigned int u[4]; short8 s; } x;
    x.u[0] = a; x.u[1] = b; x.u[2] = c; x.u[3] = d;
    return x.s;
}

__global__ __launch_bounds__(512, 2)
void blk_attn(const float* __restrict__ Q, const float* __restrict__ K,
              const float* __restrict__ V, const float* __restrict__ M,
              float* __restrict__ O) {
    int bid = blockIdx.x;
    bid = (bid & 7) * 192 + (bid >> 3);   // XCD swizzle: 1 bh resident/XCD ≈ 2.2MB < 4MB L2

    const int j  = bid & 31;
    const int bh = bid >> 5;
    const int b  = bh / NH;

    const size_t base = (size_t)bh * SEQ * DIM;
    const float* Kp = K + base;
    const float* Vp = V + base;

    const int tid  = threadIdx.x;
    const int w    = tid >> 6;      // wave 0..7, owns queries [16w, 16w+16)
    const int lane = tid & 63;
    const int lo   = lane & 15;
    const int hi   = lane >> 4;

    // span [kb0, kb0+384): W0 = tiles 0..15, W1 = tiles 8..23 (always in-bounds)
    const int  kb0 = (j == 0) ? 0 : ((j == 31) ? SEQ - 384 : 128 * j - 128);
    const bool md  = (j != 0) && (j != 31);
    const float wt0 = (j == 31) ? 0.f : (md ? 0.5f : 1.f);
    const float wt1 = (j == 0)  ? 0.f : (md ? 0.5f : 1.f);

    // ---- LDS: 112 KB ----
    __shared__ __align__(16) unsigned char smem[114688];
    auto Ks = (unsigned short (*)[64])(smem);            // [384][64]: K[key][d ^ 8*(key&7)]
    auto Vt = (unsigned short (*)[384])(smem + 49152);   // [64][384]: V^T[d][k ^ 8*((d^(d>>2))&7)]
    auto Pw = (unsigned int (*)[16][32])(smem + 98304);  // [8 waves][16 q][32 dw]

    // ---- Q fragments, scaled by log2e/8 ----
    short8 qa[2];
    {
        const float qs = 0.125f * LOG2E;
        const float* qr = Q + base + (size_t)(128 * j + 16 * w + lo) * DIM + hi * 8;
        #pragma unroll
        for (int s = 0; s < 2; ++s) {
            f32x4 a = *reinterpret_cast<const f32x4*>(qr + 32 * s);
            f32x4 c = *reinterpret_cast<const f32x4*>(qr + 32 * s + 4);
            qa[s] = mk8(pk2(a[0] * qs, a[1] * qs), pk2(a[2] * qs, a[3] * qs),
                        pk2(c[0] * qs, c[1] * qs), pk2(c[2] * qs, c[3] * qs));
        }
    }

    const int c8 = lane & 7, r8 = lane >> 3;
    const int quad = lane & 3, colq = lane >> 2;
    const int kswz = 8 * (lo & 7);
    const int pswz = 4 * (lo & 7);

    // ---- stage K: 384 rows, b128 conflict-free writes ----
    #pragma unroll
    for (int it = 0; it < 6; ++it) {
        const int row = 8 * w + r8 + 64 * it;            // row & 7 == r8
        const float* kp = Kp + (size_t)(kb0 + row) * DIM + 8 * c8;
        f32x4 a = *reinterpret_cast<const f32x4*>(kp);
        f32x4 c = *reinterpret_cast<const f32x4*>(kp + 4);
        *reinterpret_cast<short8*>(&Ks[row][(8 * c8) ^ (8 * r8)]) =
            mk8(pk2(a[0], a[1]), pk2(a[2], a[3]), pk2(c[0], c[1]), pk2(c[2], c[3]));
    }
    // ---- stage V^T: 4x4 register transpose ----
    #pragma unroll
    for (int it = 0; it < 3; ++it) {
        const int kg = w + 8 * it;                       // 0..23
        const int k0 = 16 * kg + 4 * quad;
        f32x4 vr[4];
        #pragma unroll
        for (int kk = 0; kk < 4; ++kk)
            vr[kk] = *reinterpret_cast<const f32x4*>(
                Vp + (size_t)(kb0 + k0 + kk) * DIM + 4 * colq);
        #pragma unroll
        for (int i = 0; i < 4; ++i) {
            const int d  = 4 * colq + i;
            const int gd = (d ^ (d >> 2)) & 7;
            u32x2 o;
            o[0] = pk2(vr[0][i], vr[1][i]);
            o[1] = pk2(vr[2][i], vr[3][i]);
            *reinterpret_cast<u32x2*>(&Vt[d][k0 ^ (8 * gd)]) = o;
        }
    }
    __syncthreads();   // the ONLY barrier

    // ---- QK^T swapped, all 24 tiles: st[l] = S[key=16l+4hi+r][q=lo] ----
    f32x4 st[24];
    #pragma unroll
    for (int l = 0; l < 24; ++l) { st[l][0]=0.f; st[l][1]=0.f; st[l][2]=0.f; st[l][3]=0.f; }
    __builtin_amdgcn_s_setprio(1);
    #pragma unroll
    for (int s = 0; s < 2; ++s)
        #pragma unroll
        for (int l = 0; l < 24; ++l) {
            short8 kf = *reinterpret_cast<const short8*>(
                &Ks[16 * l + lo][(32 * s + 8 * hi) ^ kswz]);
            st[l] = __builtin_amdgcn_mfma_f32_16x16x32_bf16(kf, qa[s], st[l], 0, 0, 0);
        }
    __builtin_amdgcn_s_setprio(0);

    // ---- mask add (pre-scaled by log2e) ----
    const float* Mq = M + (size_t)b * SEQ + kb0;
    #pragma unroll
    for (int l = 0; l < 24; ++l) {
        f32x4 mv = *reinterpret_cast<const f32x4*>(Mq + 16 * l + 4 * hi);
        #pragma unroll
        for (int r = 0; r < 4; ++r) st[l][r] = fmaf(mv[r], LOG2E, st[l][r]);
    }

    // ---- single max over 384 keys (q = lo, lane-local; tree) ----
    float tm[24];
    #pragma unroll
    for (int l = 0; l < 24; ++l)
        tm[l] = fmaxf(fmaxf(st[l][0], st[l][1]), fmaxf(st[l][2], st[l][3]));
    float mx = fmaxf(
        fmaxf(fmaxf(fmaxf(tm[0], tm[1]),  fmaxf(tm[2], tm[3])),
              fmaxf(fmaxf(tm[4], tm[5]),  fmaxf(tm[6], tm[7]))),
        fmaxf(fmaxf(fmaxf(tm[8], tm[9]),  fmaxf(tm[10], tm[11])),
              fmaxf(fmaxf(tm[12], tm[13]), fmaxf(tm[14], tm[15]))));
    mx = fmaxf(mx, fmaxf(fmaxf(fmaxf(tm[16], tm[17]), fmaxf(tm[18], tm[19])),
                         fmaxf(fmaxf(tm[20], tm[21]), fmaxf(tm[22], tm[23]))));
    mx = fmaxf(mx, __shfl_xor(mx, 16));
    mx = fmaxf(mx, __shfl_xor(mx, 32));

    // ---- fused PV loop: per kq = exp + region-sums + pack + LDS + MFMA ----
    float S0 = 0.f, S1 = 0.f;
    f32x4 accX[4], accY[4];
    #pragma unroll
    for (int dt = 0; dt < 4; ++dt) {
        accX[dt][0]=0.f; accX[dt][1]=0.f; accX[dt][2]=0.f; accX[dt][3]=0.f;
        accY[dt][0]=0.f; accY[dt][1]=0.f; accY[dt][2]=0.f; accY[dt][3]=0.f;
    }

    #pragma unroll
    for (int kq = 0; kq < 12; ++kq) {
        const int t0 = 2 * kq, t1 = 2 * kq + 1;
        // exp (unweighted P)
        #pragma unroll
        for (int r = 0; r < 4; ++r) st[t0][r] = exp2f(st[t0][r] - mx);
        #pragma unroll
        for (int r = 0; r < 4; ++r) st[t1][r] = exp2f(st[t1][r] - mx);
        // region sums: W0 = tiles 0..15, W1 = tiles 8..23 (kq constexpr post-unroll)
        const float ts = ((st[t0][0] + st[t0][1]) + (st[t0][2] + st[t0][3]))
                       + ((st[t1][0] + st[t1][1]) + (st[t1][2] + st[t1][3]));
        if (kq < 8) S0 += ts;
        if (kq >= 4) S1 += ts;
        // pack + per-wave LDS transpose (parity dbuf; per-wave DS in-order)
        const int pp = 16 * (kq & 1);
        u32x2 w0v, w1v;
        w0v[0] = pk2(st[t0][0], st[t0][1]);
        w0v[1] = pk2(st[t0][2], st[t0][3]);
        w1v[0] = pk2(st[t1][0], st[t1][1]);
        w1v[1] = pk2(st[t1][2], st[t1][3]);
        *reinterpret_cast<u32x2*>(&Pw[w][lo][(pp + 2 * hi)     ^ pswz]) = w0v;
        *reinterpret_cast<u32x2*>(&Pw[w][lo][(pp + 8 + 2 * hi) ^ pswz]) = w1v;
        short8 pf = *reinterpret_cast<const short8*>(&Pw[w][lo][(pp + 4 * hi) ^ pswz]);
        __builtin_amdgcn_s_setprio(1);
        #pragma unroll
        for (int dt = 0; dt < 4; ++dt) {
            const int d  = 16 * dt + lo;
            const int gd = (d ^ (d >> 2)) & 7;
            short8 vf = *reinterpret_cast<const short8*>(
                &Vt[d][(32 * kq + 8 * hi) ^ (8 * gd)]);
            if (kq < 8)
                accX[dt] = __builtin_amdgcn_mfma_f32_16x16x32_bf16(vf, pf, accX[dt], 0, 0, 0);
            if (kq >= 4)
                accY[dt] = __builtin_amdgcn_mfma_f32_16x16x32_bf16(vf, pf, accY[dt], 0, 0, 0);
        }
        __builtin_amdgcn_s_setprio(0);
    }

    // ---- finalize: lane-local (q = lo), contiguous f32x4 store ----
    S0 += __shfl_xor(S0, 16); S0 += __shfl_xor(S0, 32);
    S1 += __shfl_xor(S1, 16); S1 += __shfl_xor(S1, 32);
    const float b0 = wt0 / S0;
    const float b1 = wt1 / S1;
    float* Opr = O + base + (size_t)(128 * j + 16 * w + lo) * DIM + 4 * hi;
    #pragma unroll
    for (int dt = 0; dt < 4; ++dt) {
        f32x4 o;
        #pragma unroll
        for (int r = 0; r < 4; ++r) o[r] = b0 * accX[dt][r] + b1 * accY[dt][r];
        *reinterpret_cast<f32x4*>(Opr + 16 * dt) = o;
    }
}

extern "C" void kernel_launch(void* const* d_in, const int* in_sizes, int n_in,
                              void* d_out, int out_size, void* d_ws, size_t ws_size,
                              hipStream_t stream) {
    const float* Q = (const float*)d_in[0];
    const float* K = (const float*)d_in[1];
    const float* V = (const float*)d_in[2];
    const float* M = (const float*)d_in[3];
    float* O = (float*)d_out;
    blk_attn<<<dim3(NB * NH * (SEQ / 128)), dim3(512), 0, stream>>>(Q, K, V, M, O);
}